// Round 1
// baseline (2402.835 us; speedup 1.0000x reference)
//
#include <hip/hip_runtime.h>
#include <hip/hip_bf16.h>

// Shapes (fixed by reference): B=32, N=12, S=512, D=256, A=96
#define B_ 32
#define N_ 12
#define S_ 512
#define D_ 256
#define A_ 96

// ---------------------------------------------------------------------------
// Kernel 1: qk = emb @ Wqk + bqk   [N,S,D], then q = softmax(qk, axis=d)
// One block per (n,s) row; 256 threads = one per d.
// ---------------------------------------------------------------------------
__global__ __launch_bounds__(256) void k_qk_softmax_q(
    const float* __restrict__ emb, const float* __restrict__ Wqk,
    const float* __restrict__ bqk, float* __restrict__ qk,
    float* __restrict__ q) {
  int ns = blockIdx.x;   // n*512 + s
  int d = threadIdx.x;   // 0..255
  __shared__ float se[A_];
  __shared__ float red[8];
  if (d < A_) se[d] = emb[ns * A_ + d];
  __syncthreads();
  float acc = bqk[d];
#pragma unroll
  for (int a = 0; a < A_; ++a) acc = fmaf(se[a], Wqk[a * D_ + d], acc);
  qk[ns * D_ + d] = acc;
  // softmax over d (256 values)
  float m = acc;
  for (int off = 32; off; off >>= 1) m = fmaxf(m, __shfl_xor(m, off));
  if ((d & 63) == 0) red[d >> 6] = m;
  __syncthreads();
  m = fmaxf(fmaxf(red[0], red[1]), fmaxf(red[2], red[3]));
  float e = __expf(acc - m);
  float sum = e;
  for (int off = 32; off; off >>= 1) sum += __shfl_xor(sum, off);
  if ((d & 63) == 0) red[4 + (d >> 6)] = sum;
  __syncthreads();
  sum = red[4] + red[5] + red[6] + red[7];
  q[ns * D_ + d] = e / sum;
}

// ---------------------------------------------------------------------------
// Kernel 2: kT[n][d][s] = softmax over s of qk[n][s][d].
// One block per (n,d); 256 threads, each handles s and s+256.
// ---------------------------------------------------------------------------
__global__ __launch_bounds__(256) void k_softmax_kT(
    const float* __restrict__ qk, float* __restrict__ kT) {
  int d = blockIdx.x;   // 0..255
  int n = blockIdx.y;   // 0..11
  int s = threadIdx.x;  // 0..255
  __shared__ float red[8];
  float v0 = qk[(n * S_ + s) * D_ + d];
  float v1 = qk[(n * S_ + s + 256) * D_ + d];
  float m = fmaxf(v0, v1);
  for (int off = 32; off; off >>= 1) m = fmaxf(m, __shfl_xor(m, off));
  if ((s & 63) == 0) red[s >> 6] = m;
  __syncthreads();
  m = fmaxf(fmaxf(red[0], red[1]), fmaxf(red[2], red[3]));
  float e0 = __expf(v0 - m), e1 = __expf(v1 - m);
  float sum = e0 + e1;
  for (int off = 32; off; off >>= 1) sum += __shfl_xor(sum, off);
  if ((s & 63) == 0) red[4 + (s >> 6)] = sum;
  __syncthreads();
  sum = red[4] + red[5] + red[6] + red[7];
  float inv = 1.0f / sum;
  kT[(n * D_ + d) * S_ + s] = e0 * inv;
  kT[(n * D_ + d) * S_ + s + 256] = e1 * inv;
}

// ---------------------------------------------------------------------------
// Kernel 3: kv0[b][n] = kT[n] @ value[b][n]   ([256x512] @ [512x256])
// Block = (dblk, n, b); 256 threads; thread owns output column e (=tid) and
// 64 rows d0..d0+63 (acc[64] in VGPRs). LDS tile kTs[sl][r] so the compute
// loop reads contiguous r via float4 (ds_read_b128, broadcast).
// ---------------------------------------------------------------------------
__global__ __launch_bounds__(256) void k_kv0(
    const float* __restrict__ kT, const float* __restrict__ value,
    float* __restrict__ kv0) {
  int d0 = blockIdx.x * 64;          // 0,64,128,192
  int n = blockIdx.y, b = blockIdx.z;
  int e = threadIdx.x;
  __shared__ float kTs[128][64];     // 32 KB, [s_local][row]
  float acc[64];
#pragma unroll
  for (int r = 0; r < 64; ++r) acc[r] = 0.f;
  const float* vptr = value + ((size_t)(b * N_ + n) * S_) * D_ + e;
  for (int s0 = 0; s0 < S_; s0 += 128) {
    for (int i = threadIdx.x; i < 64 * 128; i += 256) {
      int r = i >> 7, sl = i & 127;  // coalesced global read over sl
      kTs[sl][r] = kT[(n * D_ + d0 + r) * S_ + s0 + sl];
    }
    __syncthreads();
#pragma unroll 1
    for (int sl = 0; sl < 128; ++sl) {
      float w = vptr[(s0 + sl) * D_];
      const float4* row = reinterpret_cast<const float4*>(&kTs[sl][0]);
#pragma unroll
      for (int j = 0; j < 16; ++j) {
        float4 a = row[j];
        acc[4 * j + 0] = fmaf(a.x, w, acc[4 * j + 0]);
        acc[4 * j + 1] = fmaf(a.y, w, acc[4 * j + 1]);
        acc[4 * j + 2] = fmaf(a.z, w, acc[4 * j + 2]);
        acc[4 * j + 3] = fmaf(a.w, w, acc[4 * j + 3]);
      }
    }
    __syncthreads();
  }
  float* outp = kv0 + ((size_t)(b * N_ + n) * D_ + d0) * D_ + e;
#pragma unroll
  for (int r = 0; r < 64; ++r) outp[r * D_] = acc[r];
}

// ---------------------------------------------------------------------------
// Kernel 4: out[b][n][s0:s0+64][:] = (q[n] @ kv0[b][n]) @ Wv + bv
// Two-stage per block: t = q@kv0 (via LDS-transposed q), then t@Wv + bv.
// Thread owns column c (=tid), 64 rows. tbuf reused for qT then tT.
// ---------------------------------------------------------------------------
__global__ __launch_bounds__(256) void k_out(
    const float* __restrict__ q, const float* __restrict__ kv0,
    const float* __restrict__ Wv, const float* __restrict__ bv,
    float* __restrict__ out) {
  int s0 = blockIdx.x * 64;          // 0..448
  int n = blockIdx.y, b = blockIdx.z;
  int c = threadIdx.x;
  __shared__ float tbuf[256][64];    // 64 KB, [k][row]
  // stage 0: tbuf[k][r] = q[n][s0+r][k]
  for (int i = threadIdx.x; i < 64 * 256; i += 256) {
    int k = i & 255, r = i >> 8;     // coalesced global read over k
    tbuf[k][r] = q[(n * S_ + s0 + r) * D_ + k];
  }
  __syncthreads();
  const float* kvp = kv0 + ((size_t)(b * N_ + n) * D_) * D_ + c;
  float acc[64];
#pragma unroll
  for (int r = 0; r < 64; ++r) acc[r] = 0.f;
#pragma unroll 1
  for (int k = 0; k < 256; ++k) {
    float w = kvp[k * D_];
    const float4* row = reinterpret_cast<const float4*>(&tbuf[k][0]);
#pragma unroll
    for (int j = 0; j < 16; ++j) {
      float4 a = row[j];
      acc[4 * j + 0] = fmaf(a.x, w, acc[4 * j + 0]);
      acc[4 * j + 1] = fmaf(a.y, w, acc[4 * j + 1]);
      acc[4 * j + 2] = fmaf(a.z, w, acc[4 * j + 2]);
      acc[4 * j + 3] = fmaf(a.w, w, acc[4 * j + 3]);
    }
  }
  __syncthreads();
  // stage 1: tbuf[c][r] = t[r][c]
#pragma unroll
  for (int r = 0; r < 64; ++r) tbuf[c][r] = acc[r];
  __syncthreads();
#pragma unroll
  for (int r = 0; r < 64; ++r) acc[r] = 0.f;
#pragma unroll 1
  for (int k = 0; k < 256; ++k) {
    float w = Wv[k * D_ + c];
    const float4* row = reinterpret_cast<const float4*>(&tbuf[k][0]);
#pragma unroll
    for (int j = 0; j < 16; ++j) {
      float4 a = row[j];
      acc[4 * j + 0] = fmaf(a.x, w, acc[4 * j + 0]);
      acc[4 * j + 1] = fmaf(a.y, w, acc[4 * j + 1]);
      acc[4 * j + 2] = fmaf(a.z, w, acc[4 * j + 2]);
      acc[4 * j + 3] = fmaf(a.w, w, acc[4 * j + 3]);
    }
  }
  float bvc = bv[c];
  float* op = out + ((size_t)(b * N_ + n) * S_ + s0) * D_ + c;
#pragma unroll
  for (int r = 0; r < 64; ++r) op[r * D_] = acc[r] + bvc;
}

// ---------------------------------------------------------------------------
extern "C" void kernel_launch(void* const* d_in, const int* in_sizes, int n_in,
                              void* d_out, int out_size, void* d_ws,
                              size_t ws_size, hipStream_t stream) {
  const float* value = (const float*)d_in[0];  // [B,N,S,D]
  const float* emb   = (const float*)d_in[1];  // [N,S,A]
  const float* Wqk   = (const float*)d_in[2];  // [A,D]
  const float* bqk   = (const float*)d_in[3];  // [D]
  const float* Wv    = (const float*)d_in[4];  // [D,D]
  const float* bv    = (const float*)d_in[5];  // [D]
  float* out = (float*)d_out;

  // workspace layout (floats): qk | q | kT | kv0  — total 29,884,416 f = 114 MB
  float* ws  = (float*)d_ws;
  float* qk  = ws;                       // N*S*D  = 1,572,864
  float* q   = qk + (size_t)N_ * S_ * D_;
  float* kT  = q  + (size_t)N_ * S_ * D_;   // [n][d][s]
  float* kv0 = kT + (size_t)N_ * S_ * D_;   // [b][n][d][e] = 25,165,824

  k_qk_softmax_q<<<dim3(N_ * S_), 256, 0, stream>>>(emb, Wqk, bqk, qk, q);
  k_softmax_kT<<<dim3(D_, N_), 256, 0, stream>>>(qk, kT);
  k_kv0<<<dim3(4, N_, B_), 256, 0, stream>>>(kT, value, kv0);
  k_out<<<dim3(8, N_, B_), 256, 0, stream>>>(q, kv0, Wv, bv, out);
}

// Round 2
// 483.705 us; speedup vs baseline: 4.9676x; 4.9676x over previous
//
#include <hip/hip_runtime.h>
#include <hip/hip_bf16.h>

// Shapes (fixed by reference): B=32, N=12, S=512, D=256, A=96
#define B_ 32
#define N_ 12
#define S_ 512
#define D_ 256
#define A_ 96

typedef __attribute__((ext_vector_type(8))) short short8;   // 8 bf16 (4 VGPRs)
typedef __attribute__((ext_vector_type(4))) float float4v;  // MFMA acc

// fp32 -> bf16 round-to-nearest-even (data has no NaN/Inf)
static __device__ __forceinline__ ushort f2bf(float f) {
  union { float f; unsigned u; } a;
  a.f = f;
  return (ushort)((a.u + 0x7FFFu + ((a.u >> 16) & 1u)) >> 16);
}

// ---------------------------------------------------------------------------
// Kernel 1: qk = emb @ Wqk + bqk  [N,S,D] fp32 (for kernel 2), and
//           q = softmax(qk, d) written bf16 [n][s][d].
// ---------------------------------------------------------------------------
__global__ __launch_bounds__(256) void k_qk_softmax_q(
    const float* __restrict__ emb, const float* __restrict__ Wqk,
    const float* __restrict__ bqk, float* __restrict__ qk,
    ushort* __restrict__ qb) {
  int ns = blockIdx.x;
  int d = threadIdx.x;
  __shared__ float se[A_];
  __shared__ float red[8];
  if (d < A_) se[d] = emb[ns * A_ + d];
  __syncthreads();
  float acc = bqk[d];
#pragma unroll
  for (int a = 0; a < A_; ++a) acc = fmaf(se[a], Wqk[a * D_ + d], acc);
  qk[ns * D_ + d] = acc;
  float m = acc;
  for (int off = 32; off; off >>= 1) m = fmaxf(m, __shfl_xor(m, off));
  if ((d & 63) == 0) red[d >> 6] = m;
  __syncthreads();
  m = fmaxf(fmaxf(red[0], red[1]), fmaxf(red[2], red[3]));
  float e = __expf(acc - m);
  float sum = e;
  for (int off = 32; off; off >>= 1) sum += __shfl_xor(sum, off);
  if ((d & 63) == 0) red[4 + (d >> 6)] = sum;
  __syncthreads();
  sum = red[4] + red[5] + red[6] + red[7];
  qb[ns * D_ + d] = f2bf(e / sum);
}

// ---------------------------------------------------------------------------
// Kernel 2: kT[n][d][s] = softmax over s of qk[n][s][d], bf16 output.
// ---------------------------------------------------------------------------
__global__ __launch_bounds__(256) void k_softmax_kT(
    const float* __restrict__ qk, ushort* __restrict__ kTb) {
  int d = blockIdx.x;
  int n = blockIdx.y;
  int s = threadIdx.x;
  __shared__ float red[8];
  float v0 = qk[(n * S_ + s) * D_ + d];
  float v1 = qk[(n * S_ + s + 256) * D_ + d];
  float m = fmaxf(v0, v1);
  for (int off = 32; off; off >>= 1) m = fmaxf(m, __shfl_xor(m, off));
  if ((s & 63) == 0) red[s >> 6] = m;
  __syncthreads();
  m = fmaxf(fmaxf(red[0], red[1]), fmaxf(red[2], red[3]));
  float e0 = __expf(v0 - m), e1 = __expf(v1 - m);
  float sum = e0 + e1;
  for (int off = 32; off; off >>= 1) sum += __shfl_xor(sum, off);
  if ((s & 63) == 0) red[4 + (s >> 6)] = sum;
  __syncthreads();
  sum = red[4] + red[5] + red[6] + red[7];
  float inv = 1.0f / sum;
  kTb[(n * D_ + d) * S_ + s] = f2bf(e0 * inv);
  kTb[(n * D_ + d) * S_ + s + 256] = f2bf(e1 * inv);
}

// ---------------------------------------------------------------------------
// Kernel 3: WvT[c][e] = bf16(Wv[e][c])  (tiny: 256x256)
// ---------------------------------------------------------------------------
__global__ __launch_bounds__(256) void k_wvt(const float* __restrict__ Wv,
                                             ushort* __restrict__ WvT) {
  int c = blockIdx.x, e = threadIdx.x;
  WvT[c * D_ + e] = f2bf(Wv[e * D_ + c]);
}

// ---------------------------------------------------------------------------
// Kernel 4: kv0T[bn][e][d] = sum_s kT[n][d][s] * value[bn][s][e]  (bf16 MFMA)
// NT-GEMM: C[m=d][n=e], A = kT (natural), Bt = value^T (transposed in staging).
// Block tile 128x128, 4 waves 2x2 (each 64x64 = 4x4 MFMA frags), BK=64.
// ---------------------------------------------------------------------------
__global__ __launch_bounds__(256) void k_kv0T(
    const ushort* __restrict__ kTb, const float* __restrict__ value,
    ushort* __restrict__ kv0T) {
  const int bx = blockIdx.x;  // d-tile (0..1)
  const int by = blockIdx.y;  // e-tile (0..1)
  const int bz = blockIdx.z;  // b*N+n
  const int n = bz % N_;
  const int tid = threadIdx.x;
  const int l = tid & 63, w = tid >> 6;
  const int wm = w & 1, wn = w >> 1;
  const int lane16 = l & 15, quad = l >> 4;

  __shared__ ushort ldsA[128 * 72];  // kT tile   [d_local][s_local], pad 72
  __shared__ ushort ldsB[128 * 72];  // vT tile   [e_local][s_local]

  float4v acc[4][4];
#pragma unroll
  for (int i = 0; i < 4; ++i)
#pragma unroll
    for (int j = 0; j < 4; ++j) acc[i][j] = (float4v)0.0f;

  const ushort* kTbase = kTb + ((size_t)(n * D_ + bx * 128)) * S_;
  const float* vbase = value + (size_t)bz * S_ * D_ + by * 128;

  for (int sc = 0; sc < S_; sc += 64) {
    __syncthreads();
    // stage A: 128 rows x 64 cols bf16, natural copy, 16B chunks
#pragma unroll
    for (int it = 0; it < 4; ++it) {
      int id = it * 256 + tid;
      int rd = id >> 3, cc = (id & 7) * 8;
      *(uint4*)(&ldsA[rd * 72 + cc]) =
          *(const uint4*)(kTbase + rd * S_ + sc + cc);
    }
    // stage B transposed: read value[s][e] coalesced, write ldsB[e][s]
#pragma unroll
    for (int it = 0; it < 16; ++it) {
      int id = it * 256 + tid;
      int e = id & 127, sp = id >> 7;  // sp: s-pair 0..31
      float f0 = vbase[(sc + 2 * sp) * D_ + e];
      float f1 = vbase[(sc + 2 * sp + 1) * D_ + e];
      ushort2 p;
      p.x = f2bf(f0);
      p.y = f2bf(f1);
      *(ushort2*)(&ldsB[e * 72 + 2 * sp]) = p;
    }
    __syncthreads();
#pragma unroll
    for (int kc = 0; kc < 64; kc += 32) {
      int ko = kc + quad * 8;
      short8 a[4], b[4];
#pragma unroll
      for (int i = 0; i < 4; ++i)
        a[i] = *(const short8*)(&ldsA[(wm * 64 + i * 16 + lane16) * 72 + ko]);
#pragma unroll
      for (int j = 0; j < 4; ++j)
        b[j] = *(const short8*)(&ldsB[(wn * 64 + j * 16 + lane16) * 72 + ko]);
#pragma unroll
      for (int i = 0; i < 4; ++i)
#pragma unroll
        for (int j = 0; j < 4; ++j)
          acc[i][j] = __builtin_amdgcn_mfma_f32_16x16x32_bf16(a[i], b[j],
                                                              acc[i][j], 0, 0, 0);
    }
  }
  // epilogue: C[m=d=quad*4+r][n=e=lane16] -> kv0T[e][d], 4 consecutive d packed
  ushort* obase = kv0T + (size_t)bz * D_ * D_;
#pragma unroll
  for (int i = 0; i < 4; ++i) {
#pragma unroll
    for (int j = 0; j < 4; ++j) {
      int e = by * 128 + wn * 64 + j * 16 + lane16;
      int d0 = bx * 128 + wm * 64 + i * 16 + quad * 4;
      ushort4 p;
      p.x = f2bf(acc[i][j][0]);
      p.y = f2bf(acc[i][j][1]);
      p.z = f2bf(acc[i][j][2]);
      p.w = f2bf(acc[i][j][3]);
      *(ushort4*)(obase + e * D_ + d0) = p;
    }
  }
}

// ---------------------------------------------------------------------------
// Kernel 5 (fused): per (bn, s-tile of 64):
//   stage1: t^T[e'][s] = sum_d kv0T[e'][d] * q[s][d]   (C1[e'][s], MFMA)
//           -> ldsT[s][e'] bf16 (never hits HBM)
//   stage2: out[s][c] = sum_e t[s][e] * WvT[c][e] + bv[c]
// 4 waves; stage1 wave w owns e' in [64w,64w+64); stage2 wave w owns c range.
// ---------------------------------------------------------------------------
__global__ __launch_bounds__(256) void k_out_fused(
    const ushort* __restrict__ qb, const ushort* __restrict__ kv0T,
    const ushort* __restrict__ WvT, const float* __restrict__ bv,
    float* __restrict__ out) {
  const int bx = blockIdx.x;  // s-tile (0..7)
  const int bz = blockIdx.y;  // b*N+n
  const int n = bz % N_;
  const int tid = threadIdx.x;
  const int l = tid & 63, w = tid >> 6;
  const int lane16 = l & 15, quad = l >> 4;

  __shared__ ushort smem[35328];    // 70,656 B
  ushort* ldsKV = smem;             // [256][72] stage1 B... A operand (kv0T)
  ushort* ldsQ = smem + 18432;      // [64][72]
  ushort* ldsW = smem;              // [256][72] alias (stage2)
  ushort* ldsT = smem + 18432;      // [64][264] alias (t tile, pad 264)

  const ushort* qbase = qb + ((size_t)n * S_ + bx * 64) * D_;
  const ushort* kvbase = kv0T + (size_t)bz * D_ * D_;

  float4v acc[4][4];
#pragma unroll
  for (int i = 0; i < 4; ++i)
#pragma unroll
    for (int j = 0; j < 4; ++j) acc[i][j] = (float4v)0.0f;

  // ---- stage 1: C1[e'][s] over k=d ----
  for (int dc = 0; dc < D_; dc += 64) {
    __syncthreads();
#pragma unroll
    for (int it = 0; it < 2; ++it) {  // q tile 64x64
      int id = it * 256 + tid;
      int r = id >> 3, cc = (id & 7) * 8;
      *(uint4*)(&ldsQ[r * 72 + cc]) = *(const uint4*)(qbase + r * D_ + dc + cc);
    }
#pragma unroll
    for (int it = 0; it < 8; ++it) {  // kv0T tile 256x64
      int id = it * 256 + tid;
      int r = id >> 3, cc = (id & 7) * 8;
      *(uint4*)(&ldsKV[r * 72 + cc]) =
          *(const uint4*)(kvbase + r * D_ + dc + cc);
    }
    __syncthreads();
#pragma unroll
    for (int kc = 0; kc < 64; kc += 32) {
      int ko = kc + quad * 8;
      short8 a[4], b[4];
#pragma unroll
      for (int i = 0; i < 4; ++i)  // A = kv0T rows e'
        a[i] = *(const short8*)(&ldsKV[(w * 64 + i * 16 + lane16) * 72 + ko]);
#pragma unroll
      for (int j = 0; j < 4; ++j)  // Bt = q rows s
        b[j] = *(const short8*)(&ldsQ[(j * 16 + lane16) * 72 + ko]);
#pragma unroll
      for (int i = 0; i < 4; ++i)
#pragma unroll
        for (int j = 0; j < 4; ++j)
          acc[i][j] = __builtin_amdgcn_mfma_f32_16x16x32_bf16(a[i], b[j],
                                                              acc[i][j], 0, 0, 0);
    }
  }
  __syncthreads();  // all stage-1 LDS reads done before ldsT overwrite
  // C1 row = e' = w*64+i*16+quad*4+r, col = s = j*16+lane16 -> ldsT[s][e']
#pragma unroll
  for (int i = 0; i < 4; ++i) {
#pragma unroll
    for (int j = 0; j < 4; ++j) {
      int s = j * 16 + lane16;
      int e0 = w * 64 + i * 16 + quad * 4;
      ushort4 p;
      p.x = f2bf(acc[i][j][0]);
      p.y = f2bf(acc[i][j][1]);
      p.z = f2bf(acc[i][j][2]);
      p.w = f2bf(acc[i][j][3]);
      *(ushort4*)(&ldsT[s * 264 + e0]) = p;
    }
  }

  // ---- stage 2: C2[s][c] over k=e' ----
  float4v acc2[4][4];
#pragma unroll
  for (int i = 0; i < 4; ++i)
#pragma unroll
    for (int j = 0; j < 4; ++j) acc2[i][j] = (float4v)0.0f;

  for (int ec = 0; ec < D_; ec += 64) {
    __syncthreads();  // iter0: ldsT writes + last ldsKV reads complete
#pragma unroll
    for (int it = 0; it < 8; ++it) {  // WvT tile 256x64
      int id = it * 256 + tid;
      int r = id >> 3, cc = (id & 7) * 8;
      *(uint4*)(&ldsW[r * 72 + cc]) = *(const uint4*)(WvT + r * D_ + ec + cc);
    }
    __syncthreads();
#pragma unroll
    for (int kc = 0; kc < 64; kc += 32) {
      int ko = kc + quad * 8;
      short8 a[4], b[4];
#pragma unroll
      for (int i = 0; i < 4; ++i)  // A = t rows s, k = e' (global idx in ldsT)
        a[i] = *(const short8*)(&ldsT[(i * 16 + lane16) * 264 + ec + ko]);
#pragma unroll
      for (int j = 0; j < 4; ++j)  // Bt = WvT rows c
        b[j] = *(const short8*)(&ldsW[(w * 64 + j * 16 + lane16) * 72 + ko]);
#pragma unroll
      for (int i = 0; i < 4; ++i)
#pragma unroll
        for (int j = 0; j < 4; ++j)
          acc2[i][j] = __builtin_amdgcn_mfma_f32_16x16x32_bf16(a[i], b[j],
                                                               acc2[i][j], 0, 0, 0);
    }
  }
  // epilogue: C2 row = s = i*16+quad*4+r, col = c = w*64+j*16+lane16
  float* obase = out + (size_t)bz * S_ * D_ + (size_t)bx * 64 * D_;
#pragma unroll
  for (int i = 0; i < 4; ++i) {
#pragma unroll
    for (int j = 0; j < 4; ++j) {
      int s0 = i * 16 + quad * 4;
      int c = w * 64 + j * 16 + lane16;
      float bvc = bv[c];
#pragma unroll
      for (int r = 0; r < 4; ++r)
        obase[(s0 + r) * D_ + c] = acc2[i][j][r] + bvc;
    }
  }
}

// ---------------------------------------------------------------------------
extern "C" void kernel_launch(void* const* d_in, const int* in_sizes, int n_in,
                              void* d_out, int out_size, void* d_ws,
                              size_t ws_size, hipStream_t stream) {
  const float* value = (const float*)d_in[0];  // [B,N,S,D]
  const float* emb   = (const float*)d_in[1];  // [N,S,A]
  const float* Wqk   = (const float*)d_in[2];  // [A,D]
  const float* bqk   = (const float*)d_in[3];  // [D]
  const float* Wv    = (const float*)d_in[4];  // [D,D]
  const float* bv    = (const float*)d_in[5];  // [D]
  float* out = (float*)d_out;

  // ws layout (bytes): qk fp32 [0, 6.29M) | q bf16 | kT bf16 | kv0T bf16 | WvT
  char* ws = (char*)d_ws;
  float*  qk   = (float*)ws;                         // 6,291,456 B
  ushort* qb   = (ushort*)(ws + 6291456);            // 3,145,728 B
  ushort* kTb  = (ushort*)(ws + 9437184);            // 3,145,728 B
  ushort* kv0T = (ushort*)(ws + 12582912);           // 50,331,648 B
  ushort* WvT  = (ushort*)(ws + 62914560);           // 131,072 B  (total ~63 MB)

  k_qk_softmax_q<<<dim3(N_ * S_), 256, 0, stream>>>(emb, Wqk, bqk, qk, qb);
  k_softmax_kT<<<dim3(D_, N_), 256, 0, stream>>>(qk, kTb);
  k_wvt<<<dim3(D_), 256, 0, stream>>>(Wv, WvT);
  k_kv0T<<<dim3(2, 2, B_ * N_), 256, 0, stream>>>(kTb, value, kv0T);
  k_out_fused<<<dim3(8, B_ * N_), 256, 0, stream>>>(qb, kv0T, WvT, bv, out);
}